// Round 1
// baseline (782.174 us; speedup 1.0000x reference)
//
#include <hip/hip_runtime.h>

#define NKER 84
#define NCH 9
#define SEQ 2048
#define NBATCH 64
#define NDIL 26
#define NFTOT 9996
#define MAXNF 15
#define NSLOT 12

// Static MiniRocket config for SEQ_LEN=2048, NUM_FEATURES=10000 (replicates numpy float64 logspace)
static constexpr int DILS[NDIL]   = {1,2,3,4,5,7,8,10,12,14,17,20,25,29,35,42,51,61,73,87,104,125,149,178,213,255};
static constexpr int NFDS[NDIL]   = {15,12,4,4,8,4,4,4,4,4,4,4,4,4,4,4,4,4,3,3,3,3,3,3,3,3};
static constexpr int CBASES[NDIL] = {0,1260,2268,2604,2940,3612,3948,4284,4620,4956,5292,5628,5964,6300,6636,6972,7308,7644,7980,8232,8484,8736,8988,9240,9492,9744};

// Unaligned-capable vector views of LDS: compiler picks ds_read_b128 /
// ds_read2_b64 / ds_read2_b32 per tap depending on compile-time alignment.
typedef float f32x2u __attribute__((ext_vector_type(2), aligned(4)));
typedef float f32x4u __attribute__((ext_vector_type(4), aligned(4)));

// Force a (known-uniform) float into an SGPR so v_cmp/v_fma read it scalar-side.
__device__ __forceinline__ float uniform_f(float v) {
    return __builtin_bit_cast(float, __builtin_amdgcn_readfirstlane(__builtin_bit_cast(int, v)));
}

template <int I>
__device__ __forceinline__ void body(const float* __restrict__ kw,
                                     const float* __restrict__ cc,
                                     const float* __restrict__ bias,
                                     float* __restrict__ out,
                                     const float* __restrict__ xb,   // x + b*NCH*SEQ
                                     float* __restrict__ y,
                                     int b, int slot, int lane) {
    constexpr int D = DILS[I];
    constexpr int NF = NFDS[I];
    constexpr int P = 4 * D;
    constexpr int PAD1 = I & 1;
    constexpr int CBASE = CBASES[I];
    constexpr int RANGE = SEQ - 2 * P;          // valid-region length (>0 for all D)
    // full-range loop split (compile-time): interior j has all taps in [0, SEQ) for every lane
    constexpr int JLO = (P + 63) / 64;                      // first fully-interior 64-iter
    constexpr int JHI = (SEQ - P - 64) / 64;                // last fully-interior 64-iter (incl)
    constexpr int NI  = (JHI + 1 > JLO) ? (JHI + 1 - JLO) : 0;   // # interior 64-iters
    constexpr int JT0 = (JHI + 1 > JLO) ? (JHI + 1) : JLO;  // start of trailing boundary
    // interior decomposition: quads (256 el) + optional pair (128) + optional single (64)
    constexpr int NI4 = NI / 4;
    constexpr bool IP2 = (NI & 2) != 0;
    constexpr bool IP1 = (NI & 1) != 0;
    constexpr int QB  = JLO * 64;
    constexpr int P2B = QB + NI4 * 256;
    constexpr int P1B = P2B + (IP2 ? 128 : 0);
    // valid-region decomposition: quads + optional pair + optional single + clamped partial
    constexpr int MV4 = RANGE / 256;
    constexpr bool VP2 = ((RANGE / 128) & 1) != 0;
    constexpr bool VP1 = ((RANGE / 64) & 1) != 0;
    constexpr int REM = RANGE & 63;
    constexpr int V2B = P + MV4 * 256;
    constexpr int V1B = V2B + (VP2 ? 128 : 0);
    constexpr int REMB = V1B + (VP1 ? 64 : 0);

    const float4* __restrict__ xb4 = (const float4*)xb;     // [NCH][SEQ/4]

    for (int k = slot; k < NKER; k += NSLOT) {
        // ---- per-kernel config (wave-uniform scalars) ----
        int mb = 0;
        for (int c = 0; c < NCH; ++c)
            if (cc[(I * NCH + c) * NKER + k] != 0.0f) mb |= (1 << c);
        mb = __builtin_amdgcn_readfirstlane(mb);

        int j0 = -1, j1 = -1, j2 = -1, no = 0;
        for (int j = 0; j < 9; ++j) {
            if (kw[k * 9 + j] > 0.0f) {
                if (no == 0) j0 = j; else if (no == 1) j1 = j; else j2 = j;
                ++no;
            }
        }
        j0 = __builtin_amdgcn_readfirstlane(j0);
        j1 = __builtin_amdgcn_readfirstlane(j1);
        j2 = __builtin_amdgcn_readfirstlane(j2);

        float w[9];
#pragma unroll
        for (int jj = 0; jj < 9; ++jj)
            w[jj] = (jj == j0 || jj == j1 || jj == j2) ? 2.0f : -1.0f;

        float bs[NF];
#pragma unroll
        for (int f = 0; f < NF; ++f)
            bs[f] = uniform_f(bias[(I * NKER + k) * MAXNF + f]);

        // ---- build y[t] = sum of masked channels, two half-SEQ passes ----
#pragma unroll
        for (int h = 0; h < 2; ++h) {
            float4 acc[SEQ / 512];
#pragma unroll
            for (int it = 0; it < SEQ / 512; ++it)
                acc[it] = make_float4(0.f, 0.f, 0.f, 0.f);
#pragma unroll
            for (int c = 0; c < NCH; ++c) {
                if (mb & (1 << c)) {
#pragma unroll
                    for (int it = 0; it < SEQ / 512; ++it) {
                        float4 v = xb4[c * (SEQ / 4) + h * (SEQ / 8) + it * 64 + lane];
                        acc[it].x += v.x; acc[it].y += v.y; acc[it].z += v.z; acc[it].w += v.w;
                    }
                }
            }
#pragma unroll
            for (int it = 0; it < SEQ / 512; ++it)
                ((float4*)y)[h * (SEQ / 8) + it * 64 + lane] = acc[it];
        }

        // wave-total counters: ballot+popcount accumulates in scalar regs
        int cnt[NF];
#pragma unroll
        for (int f = 0; f < NF; ++f) cnt[f] = 0;

        // 256-el quad iter: lane handles t=TB+4*lane..+3; 4 independent FMA chains
#define MRF_ITER4(TB) { \
            const int e0_ = (TB) + 4 * lane - 4 * D; \
            float C0 = 0.0f, C1 = 0.0f, C2 = 0.0f, C3 = 0.0f; \
            _Pragma("unroll") \
            for (int jj = 0; jj < 9; ++jj) { \
                f32x4u p_ = *(const f32x4u*)(y + e0_ + jj * D); \
                C0 = __builtin_fmaf(w[jj], p_.x, C0); \
                C1 = __builtin_fmaf(w[jj], p_.y, C1); \
                C2 = __builtin_fmaf(w[jj], p_.z, C2); \
                C3 = __builtin_fmaf(w[jj], p_.w, C3); \
            } \
            _Pragma("unroll") \
            for (int f = 0; f < NF; ++f) \
                cnt[f] += __popcll(__ballot(C0 > bs[f])) + __popcll(__ballot(C1 > bs[f])) \
                        + __popcll(__ballot(C2 > bs[f])) + __popcll(__ballot(C3 > bs[f])); }

        // 128-el pair iter
#define MRF_ITER2(TB) { \
            const int e0_ = (TB) + 2 * lane - 4 * D; \
            float CvA = 0.0f, CvB = 0.0f; \
            _Pragma("unroll") \
            for (int jj = 0; jj < 9; ++jj) { \
                f32x2u p_ = *(const f32x2u*)(y + e0_ + jj * D); \
                CvA = __builtin_fmaf(w[jj], p_.x, CvA); \
                CvB = __builtin_fmaf(w[jj], p_.y, CvB); \
            } \
            _Pragma("unroll") \
            for (int f = 0; f < NF; ++f) \
                cnt[f] += __popcll(__ballot(CvA > bs[f])) + __popcll(__ballot(CvB > bs[f])); }

        // 64-el unmasked iter
#define MRF_ITER(TB) { \
            const int t_ = (TB) + lane; \
            float Cv = 0.0f; \
            _Pragma("unroll") \
            for (int jj = 0; jj < 9; ++jj) \
                Cv = __builtin_fmaf(w[jj], y[t_ + (jj - 4) * D], Cv); \
            _Pragma("unroll") \
            for (int f = 0; f < NF; ++f) \
                cnt[f] += __popcll(__ballot(Cv > bs[f])); }

        // 64-el boundary iter: per-tap window is WAVE-UNIFORM in/out/straddle ->
        // scalar-branch skip (out), plain fma (in), clamped load only when straddling
#define MRF_MASKED(TB) { \
            const int t_ = (TB) + lane; \
            float Cv = 0.0f; \
            _Pragma("unroll") \
            for (int jj = 0; jj < 9; ++jj) { \
                const int lo_ = (TB) + (jj - 4) * D; \
                if (lo_ >= 0 && lo_ + 63 < SEQ) { \
                    Cv = __builtin_fmaf(w[jj], y[t_ + (jj - 4) * D], Cv); \
                } else if (lo_ + 63 >= 0 && lo_ < SEQ) { \
                    const int u_ = t_ + (jj - 4) * D; \
                    float v_ = y[u_ & (SEQ - 1)]; \
                    v_ = ((unsigned)u_ < (unsigned)SEQ) ? v_ : 0.0f; \
                    Cv = __builtin_fmaf(w[jj], v_, Cv); \
                } \
            } \
            _Pragma("unroll") \
            for (int f = 0; f < NF; ++f) \
                cnt[f] += __popcll(__ballot(Cv > bs[f])); }

        if ((k & 1) == PAD1) {
            // ===== full padded range [0, SEQ): masked lead, quad interior, masked trail =====
#pragma unroll 4
            for (int j = 0; j < JLO; ++j) MRF_MASKED(j * 64)
#pragma unroll 2
            for (int q = 0; q < NI4; ++q) MRF_ITER4(QB + q * 256)
            if constexpr (IP2) MRF_ITER2(P2B)
            if constexpr (IP1) MRF_ITER(P1B)
#pragma unroll 4
            for (int j = JT0; j < SEQ / 64; ++j) MRF_MASKED(j * 64)
        } else {
            // ===== valid region [P, SEQ-P): quad main, pair/single bridge, clamped partial =====
#pragma unroll 2
            for (int q = 0; q < MV4; ++q) MRF_ITER4(P + q * 256)
            if constexpr (VP2) MRF_ITER2(V2B)
            if constexpr (VP1) MRF_ITER(V1B)
            if constexpr (REM != 0) {   // final partial, clamped reads, poisoned lanes
                const int t = REMB + lane;
                const int tr = (t < SEQ - P) ? t : (SEQ - P - 1);
                const float* __restrict__ pb = y + tr - 4 * D;
                float Cv = 0.0f;
#pragma unroll
                for (int jj = 0; jj < 9; ++jj)
                    Cv = __builtin_fmaf(w[jj], pb[jj * D], Cv);
                Cv = (t < SEQ - P) ? Cv : -3.402823466e38f;   // poison -> never > bias
#pragma unroll
                for (int f = 0; f < NF; ++f)
                    cnt[f] += __popcll(__ballot(Cv > bs[f]));
            }
        }

#undef MRF_ITER4
#undef MRF_ITER2
#undef MRF_ITER
#undef MRF_MASKED

        // ---- write (cnt[] is already the wave total; no shuffle reduce) ----
        const bool full = ((k & 1) == PAD1);
        const float invT = full ? (1.0f / (float)SEQ) : (1.0f / (float)RANGE);
        const int pos = full ? ((k - PAD1) >> 1) : (42 + ((k - (1 - PAD1)) >> 1));
        const int colb = CBASE + pos * NF;
        if (lane == 0) {
#pragma unroll
            for (int f = 0; f < NF; ++f)
                out[(size_t)b * NFTOT + colb + f] = (float)cnt[f] * invT;
        }
    }
}

extern "C" __global__ void __launch_bounds__(64, 4)
mrf_kernel(const float* __restrict__ x, const float* __restrict__ kw,
           const float* __restrict__ cc, const float* __restrict__ bias,
           float* __restrict__ out) {
    __shared__ __align__(16) float ybuf[SEQ];   // 8 KB per 1-wave block

    // i (dilation/template case) is the SLOWEST index: at any instant the whole
    // machine executes 1-2 of the 26 unrolled bodies -> L1I-resident, and blocks
    // round-robin across all CUs -> perfect balance. (No XCD swizzle: HBM/L2
    // locality is irrelevant at 0.2% of peak BW.)
    const int idx = blockIdx.x;
    const int s = idx % NSLOT;
    const int rest = idx / NSLOT;
    const int b = rest % NBATCH;
    const int i = rest / NBATCH;            // dilation index, slowest
    const int lane = threadIdx.x & 63;

    const float* xb = x + (size_t)b * (NCH * SEQ);

    switch (i) {
#define MRF_CASE(I) case I: body<I>(kw, cc, bias, out, xb, ybuf, b, s, lane); break;
        MRF_CASE(0)  MRF_CASE(1)  MRF_CASE(2)  MRF_CASE(3)  MRF_CASE(4)
        MRF_CASE(5)  MRF_CASE(6)  MRF_CASE(7)  MRF_CASE(8)  MRF_CASE(9)
        MRF_CASE(10) MRF_CASE(11) MRF_CASE(12) MRF_CASE(13) MRF_CASE(14)
        MRF_CASE(15) MRF_CASE(16) MRF_CASE(17) MRF_CASE(18) MRF_CASE(19)
        MRF_CASE(20) MRF_CASE(21) MRF_CASE(22) MRF_CASE(23) MRF_CASE(24)
        MRF_CASE(25)
#undef MRF_CASE
    }
}

extern "C" void kernel_launch(void* const* d_in, const int* in_sizes, int n_in,
                              void* d_out, int out_size, void* d_ws, size_t ws_size,
                              hipStream_t stream) {
    (void)in_sizes; (void)n_in; (void)d_ws; (void)ws_size; (void)out_size;
    const float* x    = (const float*)d_in[0];
    const float* kw   = (const float*)d_in[1];
    const float* cc   = (const float*)d_in[2];
    const float* bias = (const float*)d_in[3];
    float* out = (float*)d_out;

    mrf_kernel<<<dim3(NDIL * NBATCH * NSLOT), dim3(64), 0, stream>>>(x, kw, cc, bias, out);
}

// Round 2
// 699.668 us; speedup vs baseline: 1.1179x; 1.1179x over previous
//
#include <hip/hip_runtime.h>

#define NKER 84
#define NCH 9
#define SEQ 2048
#define NBATCH 64
#define NDIL 26
#define NFTOT 9996
#define MAXNF 15
#define NSLOT 12
#define NXCD 8

// Static MiniRocket config for SEQ_LEN=2048, NUM_FEATURES=10000 (replicates numpy float64 logspace)
static constexpr int DILS[NDIL]   = {1,2,3,4,5,7,8,10,12,14,17,20,25,29,35,42,51,61,73,87,104,125,149,178,213,255};
static constexpr int NFDS[NDIL]   = {15,12,4,4,8,4,4,4,4,4,4,4,4,4,4,4,4,4,3,3,3,3,3,3,3,3};
static constexpr int CBASES[NDIL] = {0,1260,2268,2604,2940,3612,3948,4284,4620,4956,5292,5628,5964,6300,6636,6972,7308,7644,7980,8232,8484,8736,8988,9240,9492,9744};

// Unaligned-capable vector views of LDS: compiler picks ds_read_b128 /
// ds_read2_b64 / ds_read2_b32 per tap depending on compile-time alignment.
typedef float f32x2u __attribute__((ext_vector_type(2), aligned(4)));
typedef float f32x4u __attribute__((ext_vector_type(4), aligned(4)));

// Force a (known-uniform) float into an SGPR so v_cmp/v_fma read it scalar-side.
__device__ __forceinline__ float uniform_f(float v) {
    return __builtin_bit_cast(float, __builtin_amdgcn_readfirstlane(__builtin_bit_cast(int, v)));
}

template <int I>
__device__ __forceinline__ void body(const float* __restrict__ kw,
                                     const float* __restrict__ cc,
                                     const float* __restrict__ bias,
                                     float* __restrict__ out,
                                     const float* __restrict__ xb,   // x + b*NCH*SEQ
                                     float* __restrict__ y,
                                     int b, int slot, int lane) {
    constexpr int D = DILS[I];
    constexpr int NF = NFDS[I];
    constexpr int P = 4 * D;
    constexpr int PAD1 = I & 1;
    constexpr int CBASE = CBASES[I];
    constexpr int RANGE = SEQ - 2 * P;          // valid-region length (>0 for all D)
    // full-range loop split (compile-time): interior j has all taps in [0, SEQ) for every lane
    constexpr int JLO = (P + 63) / 64;                      // first fully-interior 64-iter
    constexpr int JHI = (SEQ - P - 64) / 64;                // last fully-interior 64-iter (incl)
    constexpr int NI  = (JHI + 1 > JLO) ? (JHI + 1 - JLO) : 0;   // # interior 64-iters
    constexpr int JT0 = (JHI + 1 > JLO) ? (JHI + 1) : JLO;  // start of trailing boundary
    // interior decomposition: quads (256 el) + optional pair (128) + optional single (64)
    constexpr int NI4 = NI / 4;
    constexpr bool IP2 = (NI & 2) != 0;
    constexpr bool IP1 = (NI & 1) != 0;
    constexpr int QB  = JLO * 64;
    constexpr int P2B = QB + NI4 * 256;
    constexpr int P1B = P2B + (IP2 ? 128 : 0);
    // valid-region decomposition: quads + optional pair + optional single + clamped partial
    constexpr int MV4 = RANGE / 256;
    constexpr bool VP2 = ((RANGE / 128) & 1) != 0;
    constexpr bool VP1 = ((RANGE / 64) & 1) != 0;
    constexpr int REM = RANGE & 63;
    constexpr int V2B = P + MV4 * 256;
    constexpr int V1B = V2B + (VP2 ? 128 : 0);
    constexpr int REMB = V1B + (VP1 ? 64 : 0);

    const float4* __restrict__ xb4 = (const float4*)xb;     // [NCH][SEQ/4]

    for (int k = slot; k < NKER; k += NSLOT) {
        // ---- per-kernel config (wave-uniform scalars) ----
        int mb = 0;
        for (int c = 0; c < NCH; ++c)
            if (cc[(I * NCH + c) * NKER + k] != 0.0f) mb |= (1 << c);
        mb = __builtin_amdgcn_readfirstlane(mb);

        int j0 = -1, j1 = -1, j2 = -1, no = 0;
        for (int j = 0; j < 9; ++j) {
            if (kw[k * 9 + j] > 0.0f) {
                if (no == 0) j0 = j; else if (no == 1) j1 = j; else j2 = j;
                ++no;
            }
        }
        j0 = __builtin_amdgcn_readfirstlane(j0);
        j1 = __builtin_amdgcn_readfirstlane(j1);
        j2 = __builtin_amdgcn_readfirstlane(j2);

        float w[9];
#pragma unroll
        for (int jj = 0; jj < 9; ++jj)
            w[jj] = (jj == j0 || jj == j1 || jj == j2) ? 2.0f : -1.0f;

        float bs[NF];
#pragma unroll
        for (int f = 0; f < NF; ++f)
            bs[f] = uniform_f(bias[(I * NKER + k) * MAXNF + f]);

        // ---- build y[t] = sum of masked channels, two half-SEQ passes ----
#pragma unroll
        for (int h = 0; h < 2; ++h) {
            float4 acc[SEQ / 512];
#pragma unroll
            for (int it = 0; it < SEQ / 512; ++it)
                acc[it] = make_float4(0.f, 0.f, 0.f, 0.f);
#pragma unroll
            for (int c = 0; c < NCH; ++c) {
                if (mb & (1 << c)) {
#pragma unroll
                    for (int it = 0; it < SEQ / 512; ++it) {
                        float4 v = xb4[c * (SEQ / 4) + h * (SEQ / 8) + it * 64 + lane];
                        acc[it].x += v.x; acc[it].y += v.y; acc[it].z += v.z; acc[it].w += v.w;
                    }
                }
            }
#pragma unroll
            for (int it = 0; it < SEQ / 512; ++it)
                ((float4*)y)[h * (SEQ / 8) + it * 64 + lane] = acc[it];
        }

        // wave-total counters: ballot+popcount accumulates in scalar regs
        int cnt[NF];
#pragma unroll
        for (int f = 0; f < NF; ++f) cnt[f] = 0;

        // 256-el quad iter: lane handles t=TB+4*lane..+3; 4 independent FMA chains
#define MRF_ITER4(TB) { \
            const int e0_ = (TB) + 4 * lane - 4 * D; \
            float C0 = 0.0f, C1 = 0.0f, C2 = 0.0f, C3 = 0.0f; \
            _Pragma("unroll") \
            for (int jj = 0; jj < 9; ++jj) { \
                f32x4u p_ = *(const f32x4u*)(y + e0_ + jj * D); \
                C0 = __builtin_fmaf(w[jj], p_.x, C0); \
                C1 = __builtin_fmaf(w[jj], p_.y, C1); \
                C2 = __builtin_fmaf(w[jj], p_.z, C2); \
                C3 = __builtin_fmaf(w[jj], p_.w, C3); \
            } \
            _Pragma("unroll") \
            for (int f = 0; f < NF; ++f) \
                cnt[f] += __popcll(__ballot(C0 > bs[f])) + __popcll(__ballot(C1 > bs[f])) \
                        + __popcll(__ballot(C2 > bs[f])) + __popcll(__ballot(C3 > bs[f])); }

        // 128-el pair iter
#define MRF_ITER2(TB) { \
            const int e0_ = (TB) + 2 * lane - 4 * D; \
            float CvA = 0.0f, CvB = 0.0f; \
            _Pragma("unroll") \
            for (int jj = 0; jj < 9; ++jj) { \
                f32x2u p_ = *(const f32x2u*)(y + e0_ + jj * D); \
                CvA = __builtin_fmaf(w[jj], p_.x, CvA); \
                CvB = __builtin_fmaf(w[jj], p_.y, CvB); \
            } \
            _Pragma("unroll") \
            for (int f = 0; f < NF; ++f) \
                cnt[f] += __popcll(__ballot(CvA > bs[f])) + __popcll(__ballot(CvB > bs[f])); }

        // 64-el unmasked iter
#define MRF_ITER(TB) { \
            const int t_ = (TB) + lane; \
            float Cv = 0.0f; \
            _Pragma("unroll") \
            for (int jj = 0; jj < 9; ++jj) \
                Cv = __builtin_fmaf(w[jj], y[t_ + (jj - 4) * D], Cv); \
            _Pragma("unroll") \
            for (int f = 0; f < NF; ++f) \
                cnt[f] += __popcll(__ballot(Cv > bs[f])); }

        // 64-el boundary iter: per-tap window is WAVE-UNIFORM in/out/straddle ->
        // scalar-branch skip (out), plain fma (in), clamped load only when straddling
#define MRF_MASKED(TB) { \
            const int t_ = (TB) + lane; \
            float Cv = 0.0f; \
            _Pragma("unroll") \
            for (int jj = 0; jj < 9; ++jj) { \
                const int lo_ = (TB) + (jj - 4) * D; \
                if (lo_ >= 0 && lo_ + 63 < SEQ) { \
                    Cv = __builtin_fmaf(w[jj], y[t_ + (jj - 4) * D], Cv); \
                } else if (lo_ + 63 >= 0 && lo_ < SEQ) { \
                    const int u_ = t_ + (jj - 4) * D; \
                    float v_ = y[u_ & (SEQ - 1)]; \
                    v_ = ((unsigned)u_ < (unsigned)SEQ) ? v_ : 0.0f; \
                    Cv = __builtin_fmaf(w[jj], v_, Cv); \
                } \
            } \
            _Pragma("unroll") \
            for (int f = 0; f < NF; ++f) \
                cnt[f] += __popcll(__ballot(Cv > bs[f])); }

        if ((k & 1) == PAD1) {
            // ===== full padded range [0, SEQ): masked lead, quad interior, masked trail =====
#pragma unroll 4
            for (int j = 0; j < JLO; ++j) MRF_MASKED(j * 64)
#pragma unroll 2
            for (int q = 0; q < NI4; ++q) MRF_ITER4(QB + q * 256)
            if constexpr (IP2) MRF_ITER2(P2B)
            if constexpr (IP1) MRF_ITER(P1B)
#pragma unroll 4
            for (int j = JT0; j < SEQ / 64; ++j) MRF_MASKED(j * 64)
        } else {
            // ===== valid region [P, SEQ-P): quad main, pair/single bridge, clamped partial =====
#pragma unroll 2
            for (int q = 0; q < MV4; ++q) MRF_ITER4(P + q * 256)
            if constexpr (VP2) MRF_ITER2(V2B)
            if constexpr (VP1) MRF_ITER(V1B)
            if constexpr (REM != 0) {   // final partial, clamped reads, poisoned lanes
                const int t = REMB + lane;
                const int tr = (t < SEQ - P) ? t : (SEQ - P - 1);
                const float* __restrict__ pb = y + tr - 4 * D;
                float Cv = 0.0f;
#pragma unroll
                for (int jj = 0; jj < 9; ++jj)
                    Cv = __builtin_fmaf(w[jj], pb[jj * D], Cv);
                Cv = (t < SEQ - P) ? Cv : -3.402823466e38f;   // poison -> never > bias
#pragma unroll
                for (int f = 0; f < NF; ++f)
                    cnt[f] += __popcll(__ballot(Cv > bs[f]));
            }
        }

#undef MRF_ITER4
#undef MRF_ITER2
#undef MRF_ITER
#undef MRF_MASKED

        // ---- write (cnt[] is already the wave total; no shuffle reduce) ----
        const bool full = ((k & 1) == PAD1);
        const float invT = full ? (1.0f / (float)SEQ) : (1.0f / (float)RANGE);
        const int pos = full ? ((k - PAD1) >> 1) : (42 + ((k - (1 - PAD1)) >> 1));
        const int colb = CBASE + pos * NF;
        if (lane == 0) {
#pragma unroll
            for (int f = 0; f < NF; ++f)
                out[(size_t)b * NFTOT + colb + f] = (float)cnt[f] * invT;
        }
    }
}

extern "C" __global__ void __launch_bounds__(64, 4)
mrf_kernel(const float* __restrict__ x, const float* __restrict__ kw,
           const float* __restrict__ cc, const float* __restrict__ bias,
           float* __restrict__ out) {
    __shared__ __align__(16) float ybuf[SEQ];   // 8 KB per 1-wave block

    // XCD-chunked bijective swizzle (PROVEN round-0 layout): XCD x owns a
    // contiguous chunk of (b,i,s) with b slowest -> concurrent blocks on an XCD
    // share ~1-2 b values -> x slices stay L2-resident (FETCH ~6 MB, not GB).
    // Round-1 measured the alternative (i slowest, no chunking): per-XCD working
    // set = all 64 b slices (4.6 MB > 4 MB L2) -> 1.75 GB of L2 misses, 1.7x slower.
    constexpr int NGRID = NDIL * NBATCH * NSLOT;       // 19968
    constexpr int CHUNK = NGRID / NXCD;                // 2496
    const int blk = (blockIdx.x % NXCD) * CHUNK + blockIdx.x / NXCD;

    const int s = blk % NSLOT;
    const int rest = blk / NSLOT;
    const int i = rest % NDIL;              // dilation index
    const int b = rest / NDIL;              // batch index (slowest)
    const int lane = threadIdx.x & 63;

    const float* xb = x + (size_t)b * (NCH * SEQ);

    switch (i) {
#define MRF_CASE(I) case I: body<I>(kw, cc, bias, out, xb, ybuf, b, s, lane); break;
        MRF_CASE(0)  MRF_CASE(1)  MRF_CASE(2)  MRF_CASE(3)  MRF_CASE(4)
        MRF_CASE(5)  MRF_CASE(6)  MRF_CASE(7)  MRF_CASE(8)  MRF_CASE(9)
        MRF_CASE(10) MRF_CASE(11) MRF_CASE(12) MRF_CASE(13) MRF_CASE(14)
        MRF_CASE(15) MRF_CASE(16) MRF_CASE(17) MRF_CASE(18) MRF_CASE(19)
        MRF_CASE(20) MRF_CASE(21) MRF_CASE(22) MRF_CASE(23) MRF_CASE(24)
        MRF_CASE(25)
#undef MRF_CASE
    }
}

extern "C" void kernel_launch(void* const* d_in, const int* in_sizes, int n_in,
                              void* d_out, int out_size, void* d_ws, size_t ws_size,
                              hipStream_t stream) {
    (void)in_sizes; (void)n_in; (void)d_ws; (void)ws_size; (void)out_size;
    const float* x    = (const float*)d_in[0];
    const float* kw   = (const float*)d_in[1];
    const float* cc   = (const float*)d_in[2];
    const float* bias = (const float*)d_in[3];
    float* out = (float*)d_out;

    mrf_kernel<<<dim3(NDIL * NBATCH * NSLOT), dim3(64), 0, stream>>>(x, kw, cc, bias, out);
}